// Round 2
// baseline (291.283 us; speedup 1.0000x reference)
//
#include <hip/hip_runtime.h>
#include <math.h>

#define Bn 256
#define Cn 3
#define Hn 224
#define Wn 224
#define Sn 20
#define Mn 10
#define NFEAT 5
#define NHID 100
#define NOUT 10

// Fully fused: one block of 256 threads does everything.
// Key identities:
//  - feat = samples.reshape(B,S,5) with samples flat over t=s*B+b means
//    output row b' consumes the 20 CONTIGUOUS flat samples t in [b'*20, b'*20+20)
//    -> thread b' computes its own samples and accumulates fs[5] in registers.
//  - adj = ones(S,S) collapses both graph convs to sums over S (h is s-independent).
//  - final FC collapses to a 10x10 matrix wsum[k][o] = sum_s w_fcf[s*10+k][o].
//  - mixture pi/cdf depend only on b_o (256x10 LDS table); the 6 gaussian params
//    depend only on bucket g=(b_o*10+m)>>8 in {0..9} (10-entry LDS table).
__global__ __launch_bounds__(256) void k_fused(
    const float* __restrict__ x, const float* __restrict__ u_cat,
    const float* __restrict__ z, const float* __restrict__ mg,
    const float* __restrict__ w1, const float* __restrict__ b1,
    const float* __restrict__ w2, const float* __restrict__ b2,
    const float* __restrict__ wf, const float* __restrict__ bf,
    float* __restrict__ out)
{
    const int b = threadIdx.x;

    __shared__ float p[6 * Mn];
    __shared__ float cdf[Bn][Mn];        // 10 KiB: per-b_o mixture CDF
    __shared__ float bk[Mn][8];          // per-bucket: mux,muy,sx,sy,r,sq,lterm
    __shared__ float lp_arr[Sn * Bn];    // 20 KiB: logprob[t]
    __shared__ float sh_gv[NOUT][Bn];    // 10 KiB
    __shared__ float sh_part[NOUT][16];
    __shared__ float sh_max[NOUT];
    __shared__ float sh_lse[NOUT];
    __shared__ float sh_wsum[NOUT * NOUT];

    if (b < 6 * Mn) p[b] = mg[b];
    __syncthreads();

    // --- per-b_o CDF (thread b computes row b) ---
    {
        float raw[Mn];
#pragma unroll
        for (int m = 0; m < Mn; ++m) raw[m] = p[((b * Mn + m) >> 8) * 6 + 0];
        float mx = raw[0];
#pragma unroll
        for (int m = 1; m < Mn; ++m) mx = fmaxf(mx, raw[m]);
        float e[Mn];
        float sum = 0.f;
#pragma unroll
        for (int m = 0; m < Mn; ++m) { e[m] = expf(raw[m] - mx); sum += e[m]; }
        float c = 0.f;
#pragma unroll
        for (int m = 0; m < Mn; ++m) { c += e[m] / sum; cdf[b][m] = c; }
    }
    // --- per-bucket gaussian params (threads 0..9) ---
    if (b < Mn) {
        const float mux = p[b * 6 + 1];
        const float muy = p[b * 6 + 2];
        const float sx  = expf(p[b * 6 + 3]);
        const float sy  = expf(p[b * 6 + 4]);
        const float r   = tanhf(p[b * 6 + 5]);
        const float omr2 = 1.f - r * r;
        const float sq = sqrtf(omr2);
        bk[b][0] = mux; bk[b][1] = muy; bk[b][2] = sx; bk[b][3] = sy;
        bk[b][4] = r;   bk[b][5] = sq;
        bk[b][6] = logf(6.283185307179586f * sx * sy * sq);
    }
    // --- collapsed final-FC weights (threads 0..99) ---
    if (b < NOUT * NOUT) {
        const int k = b / NOUT, o = b % NOUT;
        float w = 0.f;
        for (int s = 0; s < Sn; ++s) w += wf[(s * NOUT + k) * NOUT + o];
        sh_wsum[b] = w;
    }
    __syncthreads();

    // --- main sample loop: 20 contiguous flat samples per thread ---
    float fs[NFEAT] = {0.f, 0.f, 0.f, 0.f, 0.f};
    for (int sp = 0; sp < Sn; ++sp) {
        const int t  = b * Sn + sp;      // flat index; = s_o*256 + b_o
        const int bo = t & (Bn - 1);

        const float u = u_cat[t];
        int idx = 0;
        bool found = false;
#pragma unroll
        for (int m = 0; m < Mn; ++m) {
            if (!found && u < cdf[bo][m]) { idx = m; found = true; }
        }
        const int g = (bo * Mn + idx) >> 8;

        const float mux = bk[g][0], muy = bk[g][1];
        const float sx = bk[g][2], sy = bk[g][3];
        const float r = bk[g][4], sq = bk[g][5], lterm = bk[g][6];

        const float z1 = z[t * 2 + 0];
        const float z2 = z[t * 2 + 1];

        const float px = mux + sx * z1;
        const float py = muy + sy * (r * z1 + sq * z2);
        const float zx = (px - mux) / sx;
        const float zy = (py - muy) / sy;
        const float omr2 = 1.f - r * r;
        lp_arr[t] = -(zx * zx - 2.f * r * zx * zy + zy * zy) / (2.f * omr2) - lterm;

        const float lx = tanhf(px);
        const float ly = tanhf(py);
        const float vr = 0.5f * (lx + 1.f) * (float)Hn - 0.1f;   // ref uses H for both
        const float vc = 0.5f * (ly + 1.f) * (float)Hn - 0.1f;
        int row = (int)vr; row = min(max(row, 0), Hn - 1);
        int col = (int)vc; col = min(max(col, 0), Wn - 1);

        const int base = bo * Cn * Hn * Wn + row * Wn + col;
        fs[0] += x[base + 0 * Hn * Wn];
        fs[1] += x[base + 1 * Hn * Wn];
        fs[2] += x[base + 2 * Hn * Wn];
        fs[3] += lx;
        fs[4] += ly;
    }
    __syncthreads();

    // --- output 1: full_log_prob[b] = sum_s lp[s*256+b] ---
    float flp = 0.f;
#pragma unroll
    for (int s = 0; s < Sn; ++s) flp += lp_arr[s * Bn + b];
    out[Bn * NOUT + b] = flp;

    // --- gv[k] = S * (relu(fs.W1+b1) . W2)[k] + b2[k] ---
    float gv[NOUT];
#pragma unroll
    for (int k = 0; k < NOUT; ++k) gv[k] = 0.f;
    for (int j = 0; j < NHID; ++j) {
        float a = b1[j];
#pragma unroll
        for (int f = 0; f < NFEAT; ++f) a += fs[f] * w1[f * NHID + j];
        const float h = fmaxf(a, 0.f);
#pragma unroll
        for (int k = 0; k < NOUT; ++k) gv[k] += h * w2[j * NOUT + k];
    }
#pragma unroll
    for (int k = 0; k < NOUT; ++k) {
        gv[k] = (float)Sn * gv[k] + b2[k];
        sh_gv[k][b] = gv[k];
    }
    __syncthreads();

    // --- lse[k] over batch axis (log_softmax axis=0) ---
    if (b < NOUT * 16) {
        const int k = b >> 4, part = b & 15;
        float m0 = sh_gv[k][part * 16];
        for (int i = 1; i < 16; ++i) m0 = fmaxf(m0, sh_gv[k][part * 16 + i]);
        sh_part[k][part] = m0;
    }
    __syncthreads();
    if (b < NOUT) {
        float m0 = sh_part[b][0];
        for (int i = 1; i < 16; ++i) m0 = fmaxf(m0, sh_part[b][i]);
        sh_max[b] = m0;
    }
    __syncthreads();
    if (b < NOUT * 16) {
        const int k = b >> 4, part = b & 15;
        const float m0 = sh_max[k];
        float sacc = 0.f;
        for (int i = 0; i < 16; ++i) sacc += expf(sh_gv[k][part * 16 + i] - m0);
        sh_part[k][part] = sacc;
    }
    __syncthreads();
    if (b < NOUT) {
        float sacc = 0.f;
        for (int i = 0; i < 16; ++i) sacc += sh_part[b][i];
        sh_lse[b] = sh_max[b] + logf(sacc);
    }
    __syncthreads();

    // --- logits + softmax ---
    float lg[NOUT];
#pragma unroll
    for (int k = 0; k < NOUT; ++k) lg[k] = gv[k] - sh_lse[k];
    float logits[NOUT];
#pragma unroll
    for (int o = 0; o < NOUT; ++o) {
        float a = bf[o];
#pragma unroll
        for (int k = 0; k < NOUT; ++k) a += lg[k] * sh_wsum[k * NOUT + o];
        logits[o] = a;
    }
    float mxl = logits[0];
#pragma unroll
    for (int o = 1; o < NOUT; ++o) mxl = fmaxf(mxl, logits[o]);
    float ssum = 0.f;
#pragma unroll
    for (int o = 0; o < NOUT; ++o) { logits[o] = expf(logits[o] - mxl); ssum += logits[o]; }
#pragma unroll
    for (int o = 0; o < NOUT; ++o) out[b * NOUT + o] = logits[o] / ssum;
}

extern "C" void kernel_launch(void* const* d_in, const int* in_sizes, int n_in,
                              void* d_out, int out_size, void* d_ws, size_t ws_size,
                              hipStream_t stream) {
    const float* x   = (const float*)d_in[0];
    const float* u   = (const float*)d_in[1];
    const float* z   = (const float*)d_in[2];
    const float* mg  = (const float*)d_in[3];
    const float* w1  = (const float*)d_in[4];
    const float* b1  = (const float*)d_in[5];
    const float* w2  = (const float*)d_in[6];
    const float* b2  = (const float*)d_in[7];
    const float* wf  = (const float*)d_in[8];
    const float* bf  = (const float*)d_in[9];
    float* out = (float*)d_out;

    hipLaunchKernelGGL(k_fused, dim3(1), dim3(Bn), 0, stream,
                       x, u, z, mg, w1, b1, w2, b2, wf, bf, out);
}

// Round 3
// 234.986 us; speedup vs baseline: 1.2396x; 1.2396x over previous
//
#include <hip/hip_runtime.h>
#include <math.h>

#define Bn 256
#define Cn 3
#define Hn 224
#define Wn 224
#define Sn 20
#define Mn 10
#define NFEAT 5
#define NHID 100
#define NOUT 10
#define NT (Sn * Bn)   // 5120 flat samples

// K1: one thread per flat sample t = s*B + b_o. 80 blocks x 64 threads ->
// 80 CUs, 1 wave each: maximum concurrent-miss parallelism for the scattered
// 3-channel pixel gather (the only real HBM traffic, ~1 MB of cold lines).
// Bucket-level transcendentals hoisted to a 10-entry LDS table.
__global__ __launch_bounds__(64) void k_sample(
    const float* __restrict__ x, const float* __restrict__ u_cat,
    const float* __restrict__ z, const float* __restrict__ mg,
    float* __restrict__ samples, float* __restrict__ logprob)
{
    __shared__ float p[6 * Mn];
    __shared__ float bk[Mn][8];   // mux,muy,sx,sy,r,sqrt(1-r^2),logterm
    const int lt = threadIdx.x;
    const int t  = blockIdx.x * 64 + lt;      // 0..5119
    const int bo = t & (Bn - 1);              // batch index of this sample

    if (lt < 6 * Mn) p[lt] = mg[lt];
    __syncthreads();
    if (lt < Mn) {
        const float mux = p[lt * 6 + 1];
        const float muy = p[lt * 6 + 2];
        const float sx  = expf(p[lt * 6 + 3]);
        const float sy  = expf(p[lt * 6 + 4]);
        const float r   = tanhf(p[lt * 6 + 5]);
        const float sq  = sqrtf(1.f - r * r);
        bk[lt][0] = mux; bk[lt][1] = muy; bk[lt][2] = sx; bk[lt][3] = sy;
        bk[lt][4] = r;   bk[lt][5] = sq;
        bk[lt][6] = logf(6.283185307179586f * sx * sy * sq);
    }
    __syncthreads();

    // per-b_o mixture CDF in registers (value = p0[(bo*10+m)>>8])
    float raw[Mn];
#pragma unroll
    for (int m = 0; m < Mn; ++m) raw[m] = p[((bo * Mn + m) >> 8) * 6 + 0];
    float mx = raw[0];
#pragma unroll
    for (int m = 1; m < Mn; ++m) mx = fmaxf(mx, raw[m]);
    float e[Mn];
    float sum = 0.f;
#pragma unroll
    for (int m = 0; m < Mn; ++m) { e[m] = expf(raw[m] - mx); sum += e[m]; }

    const float u = u_cat[t];
    float c = 0.f;
    int idx = 0;
    bool found = false;
#pragma unroll
    for (int m = 0; m < Mn; ++m) {
        c += e[m] / sum;
        if (!found && u < c) { idx = m; found = true; }
    }
    const int g = (bo * Mn + idx) >> 8;

    const float mux = bk[g][0], muy = bk[g][1];
    const float sx = bk[g][2], sy = bk[g][3];
    const float r = bk[g][4], sq = bk[g][5], lterm = bk[g][6];

    const float z1 = z[t * 2 + 0];
    const float z2 = z[t * 2 + 1];

    const float px = mux + sx * z1;
    const float py = muy + sy * (r * z1 + sq * z2);
    const float zx = (px - mux) / sx;
    const float zy = (py - muy) / sy;
    const float omr2 = 1.f - r * r;
    logprob[t] = -(zx * zx - 2.f * r * zx * zy + zy * zy) / (2.f * omr2) - lterm;

    const float lx = tanhf(px);
    const float ly = tanhf(py);
    const float vr = 0.5f * (lx + 1.f) * (float)Hn - 0.1f;  // ref uses H for both
    const float vc = 0.5f * (ly + 1.f) * (float)Hn - 0.1f;
    int row = (int)vr; row = min(max(row, 0), Hn - 1);
    int col = (int)vc; col = min(max(col, 0), Wn - 1);

    const int base = bo * Cn * Hn * Wn + row * Wn + col;
    const int o5 = t * NFEAT;
    samples[o5 + 0] = x[base + 0 * Hn * Wn];
    samples[o5 + 1] = x[base + 1 * Hn * Wn];
    samples[o5 + 2] = x[base + 2 * Hn * Wn];
    samples[o5 + 3] = lx;
    samples[o5 + 4] = ly;
}

// K2: single block of 256 (one thread per output row b'). Row b' consumes the
// 20 CONTIGUOUS flat samples t in [b'*20, b'*20+20) (reshape identity), read
// as 25 float4s. adj=ones collapses both graph convs to S-sums; final FC
// collapses to wsum[k][o] = sum_s w_fcf[s*10+k][o].
__global__ __launch_bounds__(256) void k_head(
    const float* __restrict__ samples, const float* __restrict__ logprob,
    const float* __restrict__ w1, const float* __restrict__ b1,
    const float* __restrict__ w2, const float* __restrict__ b2,
    const float* __restrict__ wf, const float* __restrict__ bf,
    float* __restrict__ out)
{
    const int b = threadIdx.x;
    __shared__ float sh_gv[NOUT][Bn];
    __shared__ float sh_part[NOUT][16];
    __shared__ float sh_max[NOUT];
    __shared__ float sh_lse[NOUT];
    __shared__ float sh_wsum[NOUT * NOUT];

    // full_log_prob[b] = sum_s logprob[s*256+b]
    float flp = 0.f;
#pragma unroll
    for (int s = 0; s < Sn; ++s) flp += logprob[s * Bn + b];
    out[Bn * NOUT + b] = flp;

    // fs[f] = sum over this row's 20 contiguous samples; 100 floats = 25 float4
    float fs[NFEAT] = {0.f, 0.f, 0.f, 0.f, 0.f};
    const float4* sp4 = (const float4*)(samples + b * Sn * NFEAT);
#pragma unroll
    for (int v = 0; v < 25; ++v) {
        const float4 q = sp4[v];
        fs[(v * 4 + 0) % NFEAT] += q.x;
        fs[(v * 4 + 1) % NFEAT] += q.y;
        fs[(v * 4 + 2) % NFEAT] += q.z;
        fs[(v * 4 + 3) % NFEAT] += q.w;
    }

    // gv[k] = S * (relu(fs.W1+b1) . W2)[k] + b2[k]
    float gv[NOUT];
#pragma unroll
    for (int k = 0; k < NOUT; ++k) gv[k] = 0.f;
    for (int j = 0; j < NHID; ++j) {
        float a = b1[j];
#pragma unroll
        for (int f = 0; f < NFEAT; ++f) a += fs[f] * w1[f * NHID + j];
        const float h = fmaxf(a, 0.f);
#pragma unroll
        for (int k = 0; k < NOUT; ++k) gv[k] += h * w2[j * NOUT + k];
    }
#pragma unroll
    for (int k = 0; k < NOUT; ++k) {
        gv[k] = (float)Sn * gv[k] + b2[k];
        sh_gv[k][b] = gv[k];
    }

    if (b < NOUT * NOUT) {
        const int k = b / NOUT, o = b % NOUT;
        float w = 0.f;
        for (int s = 0; s < Sn; ++s) w += wf[(s * NOUT + k) * NOUT + o];
        sh_wsum[b] = w;
    }
    __syncthreads();

    // lse[k] = logsumexp over batch axis (log_softmax axis=0)
    if (b < NOUT * 16) {
        const int k = b >> 4, part = b & 15;
        float m0 = sh_gv[k][part * 16];
        for (int i = 1; i < 16; ++i) m0 = fmaxf(m0, sh_gv[k][part * 16 + i]);
        sh_part[k][part] = m0;
    }
    __syncthreads();
    if (b < NOUT) {
        float m0 = sh_part[b][0];
        for (int i = 1; i < 16; ++i) m0 = fmaxf(m0, sh_part[b][i]);
        sh_max[b] = m0;
    }
    __syncthreads();
    if (b < NOUT * 16) {
        const int k = b >> 4, part = b & 15;
        const float m0 = sh_max[k];
        float sacc = 0.f;
        for (int i = 0; i < 16; ++i) sacc += expf(sh_gv[k][part * 16 + i] - m0);
        sh_part[k][part] = sacc;
    }
    __syncthreads();
    if (b < NOUT) {
        float sacc = 0.f;
        for (int i = 0; i < 16; ++i) sacc += sh_part[b][i];
        sh_lse[b] = sh_max[b] + logf(sacc);
    }
    __syncthreads();

    // logits + softmax
    float lg[NOUT];
#pragma unroll
    for (int k = 0; k < NOUT; ++k) lg[k] = gv[k] - sh_lse[k];
    float logits[NOUT];
#pragma unroll
    for (int o = 0; o < NOUT; ++o) {
        float a = bf[o];
#pragma unroll
        for (int k = 0; k < NOUT; ++k) a += lg[k] * sh_wsum[k * NOUT + o];
        logits[o] = a;
    }
    float mxl = logits[0];
#pragma unroll
    for (int o = 1; o < NOUT; ++o) mxl = fmaxf(mxl, logits[o]);
    float ssum = 0.f;
#pragma unroll
    for (int o = 0; o < NOUT; ++o) { logits[o] = expf(logits[o] - mxl); ssum += logits[o]; }
#pragma unroll
    for (int o = 0; o < NOUT; ++o) out[b * NOUT + o] = logits[o] / ssum;
}

extern "C" void kernel_launch(void* const* d_in, const int* in_sizes, int n_in,
                              void* d_out, int out_size, void* d_ws, size_t ws_size,
                              hipStream_t stream) {
    const float* x   = (const float*)d_in[0];
    const float* u   = (const float*)d_in[1];
    const float* z   = (const float*)d_in[2];
    const float* mg  = (const float*)d_in[3];
    const float* w1  = (const float*)d_in[4];
    const float* b1  = (const float*)d_in[5];
    const float* w2  = (const float*)d_in[6];
    const float* b2  = (const float*)d_in[7];
    const float* wf  = (const float*)d_in[8];
    const float* bf  = (const float*)d_in[9];
    float* out = (float*)d_out;

    float* samples = (float*)d_ws;                 // 5120*5 floats
    float* logprob = samples + NT * NFEAT;         // 5120 floats

    hipLaunchKernelGGL(k_sample, dim3(NT / 64), dim3(64), 0, stream,
                       x, u, z, mg, samples, logprob);
    hipLaunchKernelGGL(k_head, dim3(1), dim3(Bn), 0, stream,
                       samples, logprob, w1, b1, w2, b2, wf, bf, out);
}